// Round 15
// baseline (191.619 us; speedup 1.0000x reference)
//
#include <hip/hip_runtime.h>
#include <hip/hip_bf16.h>

typedef __attribute__((ext_vector_type(8))) short bf16x8;
typedef __attribute__((ext_vector_type(4))) float f32x4;
typedef __attribute__((ext_vector_type(4))) unsigned short u16x4;
typedef unsigned short u16;

#define M_DIM 50176
#define N_DIM 768
#define K_DIM 768
#define BM 64
#define NBLK (M_DIM / BM)   // 784 = 8 * 98

__device__ __forceinline__ u16 f2bf(float f) {
    __hip_bfloat16 h = __float2bfloat16(f);
    return *reinterpret_cast<u16*>(&h);
}

__device__ __forceinline__ void gld_lds16(const void* g, void* l) {
    __builtin_amdgcn_global_load_lds(
        (const __attribute__((address_space(1))) unsigned int*)g,
        (__attribute__((address_space(3))) unsigned int*)l, 16, 0, 0);
}

// ---------------- Kernel 1: fold weights ----------------
__global__ void fold_weights(const float* __restrict__ qkv_w,
                             const float* __restrict__ qkv_b,
                             const float* __restrict__ proj_w,
                             const float* __restrict__ proj_b,
                             const float* __restrict__ pe,
                             u16* __restrict__ Bw, float* __restrict__ bias) {
    const int o = blockIdx.x;
    const int t = threadIdx.x;
    __shared__ float wv[16];
    __shared__ float bv4[4];
    __shared__ float red[4];
    if (t < 16) wv[t] = qkv_w[32 + t];
    if (t < 4)  bv4[t] = qkv_b[8 + t];
    __syncthreads();
    const float* Prow = proj_w + o * 768;
    float s = 0.f;
    for (int c = t; c < 768; c += 256) {
        int g4 = c & ~3, j = c & 3;
        float af = Prow[g4 + 0] * wv[0 * 4 + j] + Prow[g4 + 1] * wv[1 * 4 + j] +
                   Prow[g4 + 2] * wv[2 * 4 + j] + Prow[g4 + 3] * wv[3 * 4 + j];
        Bw[o * 768 + c] = f2bf(af);
        s += af * pe[c];
        s += Prow[c] * bv4[j];
    }
    #pragma unroll
    for (int off = 32; off; off >>= 1) s += __shfl_down(s, off, 64);
    if ((t & 63) == 0) red[t >> 6] = s;
    __syncthreads();
    if (t == 0) bias[o] = red[0] + red[1] + red[2] + red[3] + proj_b[o];
}

// ---------------- Kernel 2: row-block GEMM (A staged once, full-N per block) --
// Y[m,o] = sum_c bf16(X[m,c]) * Bw[o,c] + bias[o]
// Block: 64 rows x all 768 cols. A panel (64x768 bf16, swizzled, 96 KiB LDS)
// staged ONCE -> X read exactly once from L3 (154 MB vs 924 MB re-read).
// Per n-tile (6 of 128 cols): 12 K-steps, B via gld_lds dbuf (16 KiB x2),
// stage-before-compute, 1 barrier/step; dense-LDS NT epilogue (pool = dead
// B-buf1, 2x 32-row passes); next-nt B(0) prefetch overlaps the epilogue.
// 512 threads = 8 waves (4M x 2N); wave tile 16x64; acc[4] = 16 VGPR.
__global__ __launch_bounds__(512, 2)
void gemm_rowblock(const float* __restrict__ X, const u16* __restrict__ Bw,
                   const float* __restrict__ bias, float* __restrict__ Y) {
    // XCD-aware bijective swizzle: 784 blocks = 8 * 98
    const int b = blockIdx.x;
    const int bid = (b & 7) * 98 + (b >> 3);
    const long m0 = (long)bid * BM;

    const int tid = threadIdx.x;          // 0..511
    const int lane = tid & 63;
    const int w = tid >> 6;               // 0..7
    const int wrow = w >> 1;              // 0..3 (16-row band)
    const int wcol = w & 1;               // 0..1 (64-col band)

    // LDS: A [64][768] bf16 swizzled (98304 B) | Bs[0] 16K | Bs[1] 16K (=pool)
    __shared__ __align__(16) char smem[131072];
    u16* Asmem = (u16*)smem;
    u16* Bs0 = (u16*)(smem + 98304);
    u16* Bs1 = (u16*)(smem + 114688);
    float* pool = (float*)(smem + 114688);   // 16 KiB = 32 x 128 f32

    // ---- stage A panel once: f32 -> bf16, swizzle byte^((row&7)<<4) ----
    {
        const int arow = tid >> 3;        // 0..63
        const int g0 = tid & 7;
        const float4* xrow = (const float4*)(X + (m0 + arow) * K_DIM);
        u16* adst = Asmem + arow * 768;
        #pragma unroll
        for (int i = 0; i < 24; ++i) {
            int g = g0 + i * 8;           // f32x4 granule 0..191
            float4 v = xrow[g];
            u16x4 hv;
            hv.x = f2bf(v.x); hv.y = f2bf(v.y); hv.z = f2bf(v.z); hv.w = f2bf(v.w);
            int kb = (g * 8) ^ ((arow & 7) << 4);   // bf16 byte offset in 1536B row
            *(u16x4*)&adst[kb >> 1] = hv;
        }
    }
    // ---- prologue B: tile (nt=0, k=0) into Bs0 (issued before the A-wait) ----
    auto stage_b = [&](u16* buf, int n0, int k0) {
        #pragma unroll
        for (int j = 0; j < 2; ++j) {
            int rowbase = j * 64 + w * 8;
            int row = rowbase + (lane >> 3);
            const char* src = (const char*)Bw + ((long)(n0 + row) * K_DIM + k0) * 2 +
                              (((lane & 7) * 16) ^ ((row & 7) << 4));
            gld_lds16(src, (void*)&buf[rowbase * 64]);
        }
    };
    stage_b(Bs0, 0, 0);
    __syncthreads();      // A panel + B(0,0) staged

    const int arow_f = wrow * 16 + (lane & 15);      // this lane's A row
    const u16* aptr = Asmem + arow_f * 768;
    const int axor = (arow_f & 7) << 4;
    const int kq = (lane >> 4) << 4;                 // 16B k-slot within 64B half

    f32x4 acc[4];

    auto compute_step = [&](const u16* B_, int kt) {
        #pragma unroll
        for (int h = 0; h < 2; ++h) {
            int akb = (kt * 128 + h * 64 + kq) ^ axor;
            bf16x8 av = *(const bf16x8*)&aptr[akb >> 1];
            bf16x8 bv_[4];
            #pragma unroll
            for (int nf = 0; nf < 4; ++nf) {
                int r = wcol * 64 + nf * 16 + (lane & 15);
                int pb = (h * 64 + kq) ^ ((r & 7) << 4);
                bv_[nf] = *(const bf16x8*)&B_[r * 64 + (pb >> 1)];
            }
            __builtin_amdgcn_s_setprio(1);
            #pragma unroll
            for (int nf = 0; nf < 4; ++nf)
                acc[nf] = __builtin_amdgcn_mfma_f32_16x16x32_bf16(
                    av, bv_[nf], acc[nf], 0, 0, 0);
            __builtin_amdgcn_s_setprio(0);
        }
    };

    #pragma unroll 1
    for (int nt = 0; nt < 6; ++nt) {
        const int n0 = nt * 128;
        #pragma unroll
        for (int nf = 0; nf < 4; ++nf) acc[nf] = (f32x4){0.f, 0.f, 0.f, 0.f};

        // 12 K-steps; step t reads buf[t&1] (holds k-tile t); 1 barrier/step.
        #pragma unroll 1
        for (int t2 = 0; t2 < 12; t2 += 2) {
            // t = t2 (even): read Bs0
            if (t2 + 1 < 12) stage_b(Bs1, n0, (t2 + 1) * 64);
            compute_step(Bs0, t2);
            __syncthreads();
            // t = t2+1 (odd): read Bs1
            if (t2 + 3 < 12) stage_b(Bs0, n0, (t2 + 2) * 64);
            else if (t2 + 2 < 12) stage_b(Bs0, n0, (t2 + 2) * 64);   // t2=8: k=10
            else if (nt + 1 < 6) stage_b(Bs0, n0 + 128, 0);          // t2=10: next nt
            compute_step(Bs1, t2 + 1);
            __syncthreads();
        }

        // ---- epilogue: 2 passes of 32 rows via pool (= Bs1, now dead) ----
        // C/D: col = wcol*64 + nf*16 + (lane&15); row = wrow*16 + (lane>>4)*4 + r
        #pragma unroll
        for (int p = 0; p < 2; ++p) {
            if ((wrow >> 1) == p) {
                int prow_base = (wrow & 1) * 16 + ((lane >> 4) << 2);  // 0..31 local
                #pragma unroll
                for (int nf = 0; nf < 4; ++nf) {
                    int col = wcol * 64 + nf * 16 + (lane & 15);
                    float bi = bias[n0 + col];
                    #pragma unroll
                    for (int r = 0; r < 4; ++r) {
                        int prow = prow_base + r;
                        int colS = col ^ (((prow >> 2) & 1) << 4);  // 2-way max (free)
                        pool[prow * 128 + colS] = acc[nf][r] + bi;
                    }
                }
            }
            __syncthreads();
            #pragma unroll
            for (int i = 0; i < 2; ++i) {
                int chunk = i * 512 + tid;     // 0..1023
                int rl = chunk >> 5;           // 0..31
                int g = chunk & 31;
                int gs = g ^ (((rl >> 2) & 1) << 2);
                f32x4 v = *(const f32x4*)&pool[rl * 128 + gs * 4];
                __builtin_nontemporal_store(v,
                    (f32x4*)&Y[(m0 + p * 32 + rl) * N_DIM + n0 + g * 4]);
            }
            __syncthreads();    // pool (Bs1) free for next use
        }
    }
}

extern "C" void kernel_launch(void* const* d_in, const int* in_sizes, int n_in,
                              void* d_out, int out_size, void* d_ws, size_t ws_size,
                              hipStream_t stream) {
    const float* x      = (const float*)d_in[0];
    const float* qkv_w  = (const float*)d_in[1];
    const float* qkv_b  = (const float*)d_in[2];
    const float* proj_w = (const float*)d_in[3];
    const float* proj_b = (const float*)d_in[4];
    const float* pe     = (const float*)d_in[5];
    float* y = (float*)d_out;

    u16*   Bw   = (u16*)d_ws;
    float* bias = (float*)((char*)d_ws + (size_t)N_DIM * K_DIM * 2);

    fold_weights<<<768, 256, 0, stream>>>(qkv_w, qkv_b, proj_w, proj_b, pe, Bw, bias);
    gemm_rowblock<<<NBLK, 512, 0, stream>>>(x, Bw, bias, y);
}

// Round 16
// 118.680 us; speedup vs baseline: 1.6146x; 1.6146x over previous
//
#include <hip/hip_runtime.h>
#include <hip/hip_bf16.h>

typedef __attribute__((ext_vector_type(8))) short bf16x8;
typedef __attribute__((ext_vector_type(4))) float f32x4;
typedef __attribute__((ext_vector_type(4))) unsigned short u16x4;
typedef unsigned short u16;

#define M_DIM 50176
#define N_DIM 768
#define K_DIM 768

__device__ __forceinline__ u16 f2bf(float f) {
    __hip_bfloat16 h = __float2bfloat16(f);
    return *reinterpret_cast<u16*>(&h);
}

__device__ __forceinline__ void gld_lds16(const void* g, void* l) {
    __builtin_amdgcn_global_load_lds(
        (const __attribute__((address_space(1))) unsigned int*)g,
        (__attribute__((address_space(3))) unsigned int*)l, 16, 0, 0);
}

// ---------------- Kernel 1: fold weights ----------------
__global__ void fold_weights(const float* __restrict__ qkv_w,
                             const float* __restrict__ qkv_b,
                             const float* __restrict__ proj_w,
                             const float* __restrict__ proj_b,
                             const float* __restrict__ pe,
                             u16* __restrict__ Bw, float* __restrict__ bias) {
    const int o = blockIdx.x;
    const int t = threadIdx.x;
    __shared__ float wv[16];
    __shared__ float bv4[4];
    __shared__ float red[4];
    if (t < 16) wv[t] = qkv_w[32 + t];
    if (t < 4)  bv4[t] = qkv_b[8 + t];
    __syncthreads();
    const float* Prow = proj_w + o * 768;
    float s = 0.f;
    for (int c = t; c < 768; c += 256) {
        int g4 = c & ~3, j = c & 3;
        float af = Prow[g4 + 0] * wv[0 * 4 + j] + Prow[g4 + 1] * wv[1 * 4 + j] +
                   Prow[g4 + 2] * wv[2 * 4 + j] + Prow[g4 + 3] * wv[3 * 4 + j];
        Bw[o * 768 + c] = f2bf(af);
        s += af * pe[c];
        s += Prow[c] * bv4[j];
    }
    #pragma unroll
    for (int off = 32; off; off >>= 1) s += __shfl_down(s, off, 64);
    if ((t & 63) == 0) red[t >> 6] = s;
    __syncthreads();
    if (t == 0) bias[o] = red[0] + red[1] + red[2] + red[3] + proj_b[o];
}

// ---------------- Kernel 2: fused GEMM (R12 champion + micro-opts) ----------
// Y[m,o] = sum_c bf16(X[m,c]) * Bw[o,c] + bias[o]
// 128x128 tile, BK=64, 4 waves (2x2), double-buffered swizzled LDS for A and B,
// depth-2 A-reg pipeline, issue-early/write-late, ONE-barrier-equivalent drain
// cover (stages are ~1 MFMA phase old at each barrier). Dense-LDS NT epilogue.
// Micro-opts vs R12: no setprio (m190: hurts lockstep GEMM), VMEM issues
// (stage_b, load_a) hoisted before write_a's register-drain wait, K-loop
// fully unrolled (static tails).
__global__ __launch_bounds__(256, 2)
void gemm_fused(const float* __restrict__ X, const u16* __restrict__ Bw,
                const float* __restrict__ bias, float* __restrict__ Y) {
    // XCD-aware bijective swizzle: 2352 blocks = 8 * 294
    const int b = blockIdx.x;
    const int bid = (b & 7) * 294 + (b >> 3);
    const int mt = bid / 6, nt = bid - mt * 6;
    const int m0 = mt * 128, n0 = nt * 128;

    const int tid = threadIdx.x;
    const int lane = tid & 63;
    const int w = tid >> 6;
    const int wm = w >> 1, wn = w & 1;

    // 64 KB pool: As[2] | Bs[2] during K-loop; 128x128 f32 tile in epilogue.
    __shared__ __align__(16) float pool[16384];
    u16 (*As)[128 * 64] = (u16(*)[128 * 64])pool;
    u16 (*Bs)[128 * 64] = (u16(*)[128 * 64])((char*)pool + 32768);

    f32x4 acc[4][4];
    #pragma unroll
    for (int i = 0; i < 4; ++i)
        #pragma unroll
        for (int j = 0; j < 4; ++j)
            acc[i][j] = (f32x4){0.f, 0.f, 0.f, 0.f};

    const int arow = tid >> 4;      // 0..15
    const int agg  = tid & 15;      // 16B fp32 granule within row
    const int bg = lane & 7;

    float4 preA[8], preB[8];

    auto load_a = [&](float4 (&p)[8], int k0) {
        const float4* src = (const float4*)(X + (long)m0 * K_DIM + k0);
        #pragma unroll
        for (int i = 0; i < 8; ++i) {
            int r = arow + 16 * i;
            p[i] = src[(long)r * (K_DIM / 4) + agg];
        }
    };

    auto write_a = [&](int buf, const float4 (&p)[8]) {
        #pragma unroll
        for (int i = 0; i < 8; ++i) {
            int r = arow + 16 * i;
            int pb = (agg * 8) ^ ((r & 7) << 4);   // bf16 byte offset in row
            u16x4 hv;
            hv.x = f2bf(p[i].x);
            hv.y = f2bf(p[i].y);
            hv.z = f2bf(p[i].z);
            hv.w = f2bf(p[i].w);
            *(u16x4*)&As[buf][r * 64 + (pb >> 1)] = hv;
        }
    };

    auto stage_b = [&](int buf, int k0) {
        #pragma unroll
        for (int j = 0; j < 4; ++j) {
            int rowbase = j * 32 + w * 8;
            int row = rowbase + (lane >> 3);
            // pre-swizzled global source, linear LDS dest (base + lane*16)
            const char* src = (const char*)Bw + ((long)(n0 + row) * K_DIM + k0) * 2 +
                              ((bg * 16) ^ ((row & 7) << 4));
            gld_lds16(src, (void*)&Bs[buf][rowbase * 64]);
        }
    };

    auto compute = [&](int buf) {
        #pragma unroll
        for (int h = 0; h < 2; ++h) {
            bf16x8 av[4], bv_[4];
            #pragma unroll
            for (int mf = 0; mf < 4; ++mf) {
                int r = wm * 64 + mf * 16 + (lane & 15);
                int pb = (h * 64 + ((lane >> 4) << 4)) ^ ((r & 7) << 4);
                av[mf] = *(const bf16x8*)&As[buf][r * 64 + (pb >> 1)];
            }
            #pragma unroll
            for (int nf = 0; nf < 4; ++nf) {
                int r = wn * 64 + nf * 16 + (lane & 15);
                int pb = (h * 64 + ((lane >> 4) << 4)) ^ ((r & 7) << 4);
                bv_[nf] = *(const bf16x8*)&Bs[buf][r * 64 + (pb >> 1)];
            }
            #pragma unroll
            for (int mf = 0; mf < 4; ++mf)
                #pragma unroll
                for (int nf = 0; nf < 4; ++nf)
                    acc[mf][nf] = __builtin_amdgcn_mfma_f32_16x16x32_bf16(
                        av[mf], bv_[nf], acc[mf][nf], 0, 0, 0);
        }
    };

    // ---- prologue ----
    load_a(preA, 0);
    stage_b(0, 0);
    load_a(preB, 64);
    write_a(0, preA);          // waits only preA; preB + gld_lds stay in flight
    __syncthreads();

    // ---- fully unrolled K-loop: iter t computes buf t&1 ----
    // even t: stage_b(t+1)->buf1, load_a(preA,t+2), write_a(buf1,preB), compute(buf0)
    // odd  t: stage_b(t+2)->buf0, load_a(preB,t+3), write_a(buf0,preA), compute(buf1)
#define ITER_EVEN(T)                                   \
    stage_b(1, ((T) + 1) * 64);                        \
    if ((T) + 2 < 12) load_a(preA, ((T) + 2) * 64);    \
    write_a(1, preB);                                  \
    compute(0);                                        \
    __syncthreads();
#define ITER_ODD(T)                                    \
    if ((T) + 1 < 12) stage_b(0, ((T) + 1) * 64);      \
    if ((T) + 2 < 12) load_a(preB, ((T) + 2) * 64);    \
    if ((T) + 1 < 12) write_a(0, preA);                \
    compute(1);                                        \
    __syncthreads();

    ITER_EVEN(0)  ITER_ODD(1)
    ITER_EVEN(2)  ITER_ODD(3)
    ITER_EVEN(4)  ITER_ODD(5)
    ITER_EVEN(6)  ITER_ODD(7)
    ITER_EVEN(8)  ITER_ODD(9)
    ITER_EVEN(10) ITER_ODD(11)
#undef ITER_EVEN
#undef ITER_ODD
    // last barrier passed: As/Bs dead, pool free.

    // ---- epilogue stage 1: acc (+bias) -> LDS tile [128][128] f32 ----
    // C/D layout: col=lane&15, row=(lane>>4)*4+reg.
    const int colq = lane & 15;
    const int rowq = (lane >> 4) * 4;
    #pragma unroll
    for (int nf = 0; nf < 4; ++nf) {
        int col = wn * 64 + nf * 16 + colq;
        float bi = bias[n0 + col];
        #pragma unroll
        for (int mf = 0; mf < 4; ++mf) {
            int rbase = wm * 64 + mf * 16 + rowq;
            #pragma unroll
            for (int r = 0; r < 4; ++r) {
                int row = rbase + r;
                int colS = col ^ (((row >> 2) & 1) << 4);   // 2-way max (free)
                pool[row * 128 + colS] = acc[mf][nf][r] + bi;
            }
        }
    }
    __syncthreads();

    // ---- epilogue stage 2: dense 16B NT stores (full 128B lines) ----
    #pragma unroll
    for (int i = 0; i < 16; ++i) {
        int chunk = i * 256 + tid;
        int row = chunk >> 5;          // 0..127
        int g = chunk & 31;            // float4 granule in row
        int gs = g ^ (((row >> 2) & 1) << 2);
        f32x4 v = *(const f32x4*)&pool[row * 128 + gs * 4];
        __builtin_nontemporal_store(v,
            (f32x4*)&Y[(long)(m0 + row) * N_DIM + n0 + g * 4]);
    }
}

extern "C" void kernel_launch(void* const* d_in, const int* in_sizes, int n_in,
                              void* d_out, int out_size, void* d_ws, size_t ws_size,
                              hipStream_t stream) {
    const float* x      = (const float*)d_in[0];
    const float* qkv_w  = (const float*)d_in[1];
    const float* qkv_b  = (const float*)d_in[2];
    const float* proj_w = (const float*)d_in[3];
    const float* proj_b = (const float*)d_in[4];
    const float* pe     = (const float*)d_in[5];
    float* y = (float*)d_out;

    u16*   Bw   = (u16*)d_ws;
    float* bias = (float*)((char*)d_ws + (size_t)N_DIM * K_DIM * 2);

    fold_weights<<<768, 256, 0, stream>>>(qkv_w, qkv_b, proj_w, proj_b, pe, Bw, bias);
    gemm_fused<<<(M_DIM / 128) * (N_DIM / 128), 256, 0, stream>>>(x, Bw, bias, y);
}

// Round 17
// 100.625 us; speedup vs baseline: 1.9043x; 1.1794x over previous
//
#include <hip/hip_runtime.h>
#include <hip/hip_bf16.h>

typedef __attribute__((ext_vector_type(8))) short bf16x8;
typedef __attribute__((ext_vector_type(4))) float f32x4;
typedef __attribute__((ext_vector_type(4))) unsigned short u16x4;
typedef unsigned short u16;

#define M_DIM 50176
#define N_DIM 768
#define K_DIM 768

__device__ __forceinline__ u16 f2bf(float f) {
    __hip_bfloat16 h = __float2bfloat16(f);
    return *reinterpret_cast<u16*>(&h);
}

__device__ __forceinline__ void gld_lds16(const void* g, void* l) {
    __builtin_amdgcn_global_load_lds(
        (const __attribute__((address_space(1))) unsigned int*)g,
        (__attribute__((address_space(3))) unsigned int*)l, 16, 0, 0);
}

// ---------------- Kernel 1: fold weights ----------------
__global__ void fold_weights(const float* __restrict__ qkv_w,
                             const float* __restrict__ qkv_b,
                             const float* __restrict__ proj_w,
                             const float* __restrict__ proj_b,
                             const float* __restrict__ pe,
                             u16* __restrict__ Bw, float* __restrict__ bias) {
    const int o = blockIdx.x;
    const int t = threadIdx.x;
    __shared__ float wv[16];
    __shared__ float bv4[4];
    __shared__ float red[4];
    if (t < 16) wv[t] = qkv_w[32 + t];
    if (t < 4)  bv4[t] = qkv_b[8 + t];
    __syncthreads();
    const float* Prow = proj_w + o * 768;
    float s = 0.f;
    for (int c = t; c < 768; c += 256) {
        int g4 = c & ~3, j = c & 3;
        float af = Prow[g4 + 0] * wv[0 * 4 + j] + Prow[g4 + 1] * wv[1 * 4 + j] +
                   Prow[g4 + 2] * wv[2 * 4 + j] + Prow[g4 + 3] * wv[3 * 4 + j];
        Bw[o * 768 + c] = f2bf(af);
        s += af * pe[c];
        s += Prow[c] * bv4[j];
    }
    #pragma unroll
    for (int off = 32; off; off >>= 1) s += __shfl_down(s, off, 64);
    if ((t & 63) == 0) red[t >> 6] = s;
    __syncthreads();
    if (t == 0) bias[o] = red[0] + red[1] + red[2] + red[3] + proj_b[o];
}

// ---------------- Kernel 2: fused GEMM (R12 champion, verbatim) -------------
// Y[m,o] = sum_c bf16(X[m,c]) * Bw[o,c] + bias[o]
// R2 structure: 128x128 tile, BK=64, 4 waves (2x2), double-buffered swizzled
// LDS for A and B, depth-2 A-reg pipeline, issue-early/write-late, setprio(1)
// around MFMA (arbitrates between the 2 resident blocks' phases).
// NT stores keep Y out of L3 so X stays L3-resident across warm replays.
// Epilogue routes acc through LDS (aliased over dead As/Bs) and emits dense
// 16B NT stores (full 128B lines) — WRITE_SIZE exactly 150528 KB.
__global__ __launch_bounds__(256, 2)
void gemm_fused(const float* __restrict__ X, const u16* __restrict__ Bw,
                const float* __restrict__ bias, float* __restrict__ Y) {
    // XCD-aware bijective swizzle: 2352 blocks = 8 * 294
    const int b = blockIdx.x;
    const int bid = (b & 7) * 294 + (b >> 3);
    const int mt = bid / 6, nt = bid - mt * 6;
    const int m0 = mt * 128, n0 = nt * 128;

    const int tid = threadIdx.x;
    const int lane = tid & 63;
    const int w = tid >> 6;
    const int wm = w >> 1, wn = w & 1;

    // 64 KB pool: staging (As 2x16K | Bs 2x16K) in the K-loop,
    // then reused as a 128x128 f32 output tile in the epilogue.
    __shared__ __align__(16) float pool[16384];
    u16 (*As)[128 * 64] = (u16(*)[128 * 64])pool;
    u16 (*Bs)[128 * 64] = (u16(*)[128 * 64])((char*)pool + 32768);

    f32x4 acc[4][4];
    #pragma unroll
    for (int i = 0; i < 4; ++i)
        #pragma unroll
        for (int j = 0; j < 4; ++j)
            acc[i][j] = (f32x4){0.f, 0.f, 0.f, 0.f};

    const int arow = tid >> 4;      // 0..15
    const int agg  = tid & 15;      // 16B fp32 granule within row
    const int bg = lane & 7;

    float4 preA[8], preB[8];

    auto load_a = [&](float4 (&p)[8], int k0) {
        const float4* src = (const float4*)(X + (long)m0 * K_DIM + k0);
        #pragma unroll
        for (int i = 0; i < 8; ++i) {
            int r = arow + 16 * i;
            p[i] = src[(long)r * (K_DIM / 4) + agg];
        }
    };

    auto write_a = [&](int buf, const float4 (&p)[8]) {
        #pragma unroll
        for (int i = 0; i < 8; ++i) {
            int r = arow + 16 * i;
            int pb = (agg * 8) ^ ((r & 7) << 4);   // bf16 byte offset in row
            u16x4 hv;
            hv.x = f2bf(p[i].x);
            hv.y = f2bf(p[i].y);
            hv.z = f2bf(p[i].z);
            hv.w = f2bf(p[i].w);
            *(u16x4*)&As[buf][r * 64 + (pb >> 1)] = hv;
        }
    };

    auto stage_b = [&](int buf, int k0) {
        #pragma unroll
        for (int j = 0; j < 4; ++j) {
            int rowbase = j * 32 + w * 8;
            int row = rowbase + (lane >> 3);
            // pre-swizzled global source, linear LDS dest (base + lane*16)
            const char* src = (const char*)Bw + ((long)(n0 + row) * K_DIM + k0) * 2 +
                              ((bg * 16) ^ ((row & 7) << 4));
            gld_lds16(src, (void*)&Bs[buf][rowbase * 64]);
        }
    };

    auto compute = [&](int buf) {
        #pragma unroll
        for (int h = 0; h < 2; ++h) {
            bf16x8 av[4], bv_[4];
            #pragma unroll
            for (int mf = 0; mf < 4; ++mf) {
                int r = wm * 64 + mf * 16 + (lane & 15);
                int pb = (h * 64 + ((lane >> 4) << 4)) ^ ((r & 7) << 4);
                av[mf] = *(const bf16x8*)&As[buf][r * 64 + (pb >> 1)];
            }
            #pragma unroll
            for (int nf = 0; nf < 4; ++nf) {
                int r = wn * 64 + nf * 16 + (lane & 15);
                int pb = (h * 64 + ((lane >> 4) << 4)) ^ ((r & 7) << 4);
                bv_[nf] = *(const bf16x8*)&Bs[buf][r * 64 + (pb >> 1)];
            }
            __builtin_amdgcn_s_setprio(1);
            #pragma unroll
            for (int mf = 0; mf < 4; ++mf)
                #pragma unroll
                for (int nf = 0; nf < 4; ++nf)
                    acc[mf][nf] = __builtin_amdgcn_mfma_f32_16x16x32_bf16(
                        av[mf], bv_[nf], acc[mf][nf], 0, 0, 0);
            __builtin_amdgcn_s_setprio(0);
        }
    };

    // ---- prologue ----
    load_a(preA, 0);
    stage_b(0, 0);
    load_a(preB, 64);
    write_a(0, preA);          // waits only on preA loads; preB + gld_lds stay in flight
    __syncthreads();

    const int NT = K_DIM / 64;  // 12
    #pragma unroll 1
    for (int t2 = 0; t2 < NT; t2 += 2) {
        // ---- even iter t=t2: compute buf 0 ----
        if (t2 + 1 < NT) {
            write_a(1, preB);              // A for t+1 (regs drained by prev barrier)
            stage_b(1, (t2 + 1) * 64);     // B for t+1
        }
        if (t2 + 2 < NT) load_a(preA, (t2 + 2) * 64);  // A regs for t+2
        compute(0);
        __syncthreads();

        // ---- odd iter t=t2+1: compute buf 1 ----
        if (t2 + 2 < NT) {
            write_a(0, preA);
            stage_b(0, (t2 + 2) * 64);
        }
        if (t2 + 3 < NT) load_a(preB, (t2 + 3) * 64);
        compute(1);
        __syncthreads();
    }
    // final loop barrier already passed: As/Bs are dead, pool is free.

    // ---- epilogue stage 1: acc (+bias) -> LDS tile [128][128] f32 ----
    // C/D layout: col=lane&15, row=(lane>>4)*4+reg.
    // Bank swizzle: col' = col ^ (((row>>2)&1)<<4) -> 2-way conflicts only (free).
    const int colq = lane & 15;
    const int rowq = (lane >> 4) * 4;
    #pragma unroll
    for (int nf = 0; nf < 4; ++nf) {
        int col = wn * 64 + nf * 16 + colq;
        float bi = bias[n0 + col];
        #pragma unroll
        for (int mf = 0; mf < 4; ++mf) {
            int rbase = wm * 64 + mf * 16 + rowq;
            #pragma unroll
            for (int r = 0; r < 4; ++r) {
                int row = rbase + r;
                int colS = col ^ (((row >> 2) & 1) << 4);
                pool[row * 128 + colS] = acc[mf][nf][r] + bi;
            }
        }
    }
    __syncthreads();

    // ---- epilogue stage 2: dense 16B NT stores (full 128B lines) ----
    // 4096 float4 chunks; consecutive tids cover consecutive 16B within a row.
    #pragma unroll
    for (int i = 0; i < 16; ++i) {
        int chunk = i * 256 + tid;
        int row = chunk >> 5;          // 0..127
        int g = chunk & 31;            // float4 index within row
        int gs = g ^ (((row >> 2) & 1) << 2);
        f32x4 v = *(const f32x4*)&pool[row * 128 + gs * 4];
        __builtin_nontemporal_store(v,
            (f32x4*)&Y[(long)(m0 + row) * N_DIM + n0 + g * 4]);
    }
}

extern "C" void kernel_launch(void* const* d_in, const int* in_sizes, int n_in,
                              void* d_out, int out_size, void* d_ws, size_t ws_size,
                              hipStream_t stream) {
    const float* x      = (const float*)d_in[0];
    const float* qkv_w  = (const float*)d_in[1];
    const float* qkv_b  = (const float*)d_in[2];
    const float* proj_w = (const float*)d_in[3];
    const float* proj_b = (const float*)d_in[4];
    const float* pe     = (const float*)d_in[5];
    float* y = (float*)d_out;

    u16*   Bw   = (u16*)d_ws;
    float* bias = (float*)((char*)d_ws + (size_t)N_DIM * K_DIM * 2);

    fold_weights<<<768, 256, 0, stream>>>(qkv_w, qkv_b, proj_w, proj_b, pe, Bw, bias);
    gemm_fused<<<(M_DIM / 128) * (N_DIM / 128), 256, 0, stream>>>(x, Bw, bias, y);
}